// Round 1
// 1137.605 us; speedup vs baseline: 1.2212x; 1.2212x over previous
//
#include <hip/hip_runtime.h>
#include <hip/hip_bf16.h>

#define B   64
#define T   512
#define DIN 64
#define F   64
#define U   128
#define G3  384     // 3U
#define M2  256     // 2U
#define NH  4
#define KD  128
#define HD  512     // NH*KD
#define BT  (B*T)   // 32768

typedef __attribute__((ext_vector_type(8))) short short8;
typedef __attribute__((ext_vector_type(4))) float floatx4;
typedef __attribute__((ext_vector_type(4))) unsigned short ushort4_t;
typedef __hip_bfloat16 bf16;

// exp2/sigmoid rescale constants (folded into weights, biases, x-gates):
//   z,r gates scaled by -log2(e)  ->  sigmoid(a) = rcp(1 + exp2(s*a))
//   n gate scaled by 2*log2(e)    ->  tanh(a)    = 1 - 2*rcp(1 + exp2(s*a))
#define GS_ZR (-1.4426950408889634f)
#define GS_N  ( 2.8853900817779268f)

// ---------------- fused weight transpose+cast: 9 segments + out-init, one launch ----------------
__device__ __forceinline__ void wcast_seg(const float* __restrict__ src,
        bf16* __restrict__ dst, int K, int N, int i)
{
    if (i < K*N) {
        const int k = i / N, n = i - k*N;
        dst[n*K + k] = __float2bfloat16(src[i]);
    }
}

__global__ __launch_bounds__(256) void k_wcast_all(
        const float* __restrict__ s0, const float* __restrict__ s1,
        const float* __restrict__ s2, const float* __restrict__ s3,
        const float* __restrict__ s4, const float* __restrict__ s5,
        const float* __restrict__ s6, const float* __restrict__ s7,
        const float* __restrict__ s8, const float* __restrict__ db,
        float* __restrict__ outp, bf16* __restrict__ wb)
{
    const int i = blockIdx.x*256 + threadIdx.x;
    switch (blockIdx.y) {
        case 0: wcast_seg(s0, wb,          64,  384, i); break;
        case 1: wcast_seg(s1, wb + 24576,  64,  384, i); break;
        case 2: wcast_seg(s2, wb + 49152,  256, 512, i); break;
        case 3: wcast_seg(s3, wb + 180224, 256, 512, i); break;
        case 4: wcast_seg(s4, wb + 311296, 256, 512, i); break;
        case 5: wcast_seg(s5, wb + 442368, 512, 256, i); break;
        case 6: wcast_seg(s6, wb + 573440, 256, 384, i); break;
        case 7: wcast_seg(s7, wb + 671744, 256, 384, i); break;
        case 8: wcast_seg(s8, wb + 770048, 192, 64,  i);   // conv cw [3*64,64] -> cwT [64,192]
                if (blockIdx.x == 0 && threadIdx.x < B) outp[threadIdx.x] = db[0];
                break;
    }
}

// ---------------- fused conv1d+BN+ReLU (MFMA, free im2col) + xg1 f/b GEMMs ----------------
// Block = 128 t-rows of one batch; grid (4, 64); 256 thr = 4 waves.
// Phase 1: x1 = relu((im2col(in) @ cwT^T)*scale + shift2), kept in LDS (pad-72).
//   A-frag addr (m+tap)*72 + (kt&1)*32 + quad*8  (tap = kt>>1, constant per kt) —
//   im2col is pure addressing. Banks: 36 dwords/row = 4 mod 32 -> 2-way (free).
// Phase 2: xg1{f,b} = x1(128x64) @ g1{f,b}T^T, 6 col-tiles of 128, K=64.
//   Epilogue scales x-gates by GS_ZR / GS_N for the exp2-domain GRU.
__global__ __launch_bounds__(256) void k_conv_xg(const float* __restrict__ in,
        const bf16* __restrict__ cwT, const float* __restrict__ cb,
        const float* __restrict__ gamma, const float* __restrict__ beta,
        const float* __restrict__ mean, const float* __restrict__ var,
        const bf16* __restrict__ g1fT, const bf16* __restrict__ g1bT,
        const float* __restrict__ g1f_b, const float* __restrict__ g1b_b,
        bf16* __restrict__ xg1f, bf16* __restrict__ xg1b)
{
    __shared__ short in_s[130*72];    // 18720 B, bf16 input rows t0-1 .. t0+128
    __shared__ short x1_s[128*72];    // 18432 B, conv output tile
    __shared__ short Bs[128*32];      //  8192 B, weight staging (both phases)
    __shared__ float scale_s[64], shift_s[64];
    const int tc = blockIdx.x;        // t-chunk
    const int b  = blockIdx.y;
    const int t0 = tc*128;
    const int tid  = threadIdx.x;
    const int lane = tid & 63;
    const int wv   = tid >> 6;
    const int l16  = lane & 15;
    const int quad = lane >> 4;

    // stage input rows (fp32 -> bf16), zero-pad out-of-range t
    for (int idx = tid; idx < 130*64; idx += 256) {
        const int row = idx >> 6, d = idx & 63;
        const int t = t0 - 1 + row;
        float v = (t >= 0 && t < T) ? in[((size_t)b*T + t)*DIN + d] : 0.0f;
        bf16 h = __float2bfloat16(v);
        in_s[row*72 + d] = *reinterpret_cast<short*>(&h);
    }
    if (tid < 64) {
        const float sc = gamma[tid] * rsqrtf(var[tid] + 1e-3f);
        scale_s[tid] = sc;
        shift_s[tid] = beta[tid] - mean[tid]*sc + cb[tid]*sc;
    }
    __syncthreads();

    // phase 1: conv GEMM  M=128 (wave: 32 rows), N=64, K=192 (6 kt)
    {
        floatx4 acc[2][4];
        #pragma unroll
        for (int i = 0; i < 2; ++i)
            #pragma unroll
            for (int j = 0; j < 4; ++j) acc[i][j] = (floatx4)0.0f;
        for (int kt = 0; kt < 6; ++kt) {
            __syncthreads();
            {   // stage cwT tile [64 rows][32 k]: 4 thr/row, 8 shorts each
                const int row = tid >> 2, koff = (tid & 3)*8;
                *reinterpret_cast<float4*>(&Bs[row*32 + koff]) =
                    *reinterpret_cast<const float4*>(&cwT[row*192 + kt*32 + koff]);
            }
            __syncthreads();
            const int tap = kt >> 1, d0 = (kt & 1)*32 + quad*8;
            short8 bf[4];
            #pragma unroll
            for (int j = 0; j < 4; ++j)
                bf[j] = *reinterpret_cast<const short8*>(&Bs[(j*16 + l16)*32 + quad*8]);
            #pragma unroll
            for (int i = 0; i < 2; ++i) {
                const short8 af = *reinterpret_cast<const short8*>(
                    &in_s[(wv*32 + i*16 + l16 + tap)*72 + d0]);
                #pragma unroll
                for (int j = 0; j < 4; ++j)
                    acc[i][j] = __builtin_amdgcn_mfma_f32_16x16x32_bf16(af, bf[j], acc[i][j], 0, 0, 0);
            }
        }
        // epilogue: BN+ReLU -> x1_s
        #pragma unroll
        for (int j = 0; j < 4; ++j) {
            const int col = j*16 + l16;
            const float sc = scale_s[col], sh = shift_s[col];
            #pragma unroll
            for (int i = 0; i < 2; ++i)
                #pragma unroll
                for (int r = 0; r < 4; ++r) {
                    const int m = wv*32 + i*16 + quad*4 + r;
                    const float v = fmaxf(acc[i][j][r]*sc + sh, 0.0f);
                    bf16 h = __float2bfloat16(v);
                    x1_s[m*72 + col] = *reinterpret_cast<short*>(&h);
                }
        }
    }
    __syncthreads();

    // phase 2: xg1 = x1 @ g1T^T, 6 col-tiles (0-2: fwd, 3-5: bwd), K=64 (2 kt)
    const int wm = wv & 1, wn = wv >> 1;
    const size_t rbase = (size_t)b*T + t0;
    for (int ct = 0; ct < 6; ++ct) {
        const bf16* Bt = (ct < 3 ? g1fT : g1bT) + (ct % 3)*128*64;
        const float* bias = (ct < 3 ? g1f_b : g1b_b);
        bf16* outp = (ct < 3 ? xg1f : xg1b);
        const int cbase = (ct % 3)*128;
        const float gs = ((ct % 3) == 2) ? GS_N : GS_ZR;   // exp2-domain gate scale
        floatx4 acc[4][4];
        #pragma unroll
        for (int i = 0; i < 4; ++i)
            #pragma unroll
            for (int j = 0; j < 4; ++j) acc[i][j] = (floatx4)0.0f;
        for (int kt = 0; kt < 2; ++kt) {
            __syncthreads();
            {   // stage weight tile [128 rows][32 k]: 2 thr/row, 16 shorts each
                const int row = tid >> 1, koff = (tid & 1)*16;
                const float4* g = reinterpret_cast<const float4*>(&Bt[(size_t)row*64 + kt*32 + koff]);
                float4* l = reinterpret_cast<float4*>(&Bs[row*32 + koff]);
                l[0] = g[0]; l[1] = g[1];
            }
            __syncthreads();
            short8 af[4], bf[4];
            #pragma unroll
            for (int i = 0; i < 4; ++i)
                af[i] = *reinterpret_cast<const short8*>(
                    &x1_s[(wm*64 + i*16 + l16)*72 + kt*32 + quad*8]);
            #pragma unroll
            for (int j = 0; j < 4; ++j)
                bf[j] = *reinterpret_cast<const short8*>(&Bs[(wn*64 + j*16 + l16)*32 + quad*8]);
            #pragma unroll
            for (int i = 0; i < 4; ++i)
                #pragma unroll
                for (int j = 0; j < 4; ++j)
                    acc[i][j] = __builtin_amdgcn_mfma_f32_16x16x32_bf16(af[i], bf[j], acc[i][j], 0, 0, 0);
        }
        #pragma unroll
        for (int j = 0; j < 4; ++j) {
            const int colg = cbase + wn*64 + j*16 + l16;
            const float bj = bias[colg];
            #pragma unroll
            for (int i = 0; i < 4; ++i)
                #pragma unroll
                for (int r = 0; r < 4; ++r) {
                    const int grow = wm*64 + i*16 + quad*4 + r;
                    outp[(rbase + grow)*G3 + colg] = __float2bfloat16((acc[i][j][r] + bj) * gs);
                }
        }
    }
}

// ------------- triple GEMM: z=0 Q, z=1 K (row-tiled), z=2 V^T (transposed shape) -------------
__global__ __launch_bounds__(256) void k_gemm3(const bf16* __restrict__ y1h,
        const bf16* __restrict__ wqT, const bf16* __restrict__ wkT,
        const bf16* __restrict__ wvT, const float* __restrict__ bq,
        const float* __restrict__ bk, const float* __restrict__ bv,
        bf16* __restrict__ qh, bf16* __restrict__ kh, bf16* __restrict__ vtg)
{
    const int z = blockIdx.z;
    const bf16* A;  const bf16* Bt;  const float* bias;  bf16* outH;
    int rbase, nbase, N, biasRow;
    if (z < 2) {
        A = y1h;  Bt = z ? wkT : wqT;  bias = z ? bk : bq;  outH = z ? kh : qh;
        rbase = blockIdx.y*128;  nbase = blockIdx.x*128;  N = HD;  biasRow = 0;
    } else {
        A = wvT;  Bt = y1h;  bias = bv;  outH = vtg;
        rbase = blockIdx.x*128;  nbase = blockIdx.y*128;  N = BT;  biasRow = 1;
    }
    const int K = 256;

    __shared__ short As[128*32];
    __shared__ short Bs[128*32];
    const int tid  = threadIdx.x;
    const int lane = tid & 63;
    const int wv   = tid >> 6;
    const int wm   = wv & 1;
    const int wn   = wv >> 1;
    const int l16  = lane & 15;
    const int quad = lane >> 4;

    floatx4 acc[4][4];
    #pragma unroll
    for (int i = 0; i < 4; ++i)
        #pragma unroll
        for (int j = 0; j < 4; ++j) acc[i][j] = (floatx4)0.0f;

    const int row  = tid >> 1;
    const int koff = (tid & 1) * 16;
    for (int kt = 0; kt < 8; ++kt) {
        if (kt) __syncthreads();
        {
            const float4* ga = reinterpret_cast<const float4*>(
                &A[(size_t)(rbase + row)*K + kt*32 + koff]);
            const float4 a0 = ga[0], a1 = ga[1];
            const float4* gb = reinterpret_cast<const float4*>(
                &Bt[(size_t)(nbase + row)*K + kt*32 + koff]);
            const float4 b0 = gb[0], b1 = gb[1];
            float4* la = reinterpret_cast<float4*>(&As[row*32 + koff]);
            la[0] = a0; la[1] = a1;
            float4* lb = reinterpret_cast<float4*>(&Bs[row*32 + koff]);
            lb[0] = b0; lb[1] = b1;
        }
        __syncthreads();
        short8 af[4], bf[4];
        #pragma unroll
        for (int i = 0; i < 4; ++i)
            af[i] = *reinterpret_cast<const short8*>(&As[(wm*64 + i*16 + l16)*32 + quad*8]);
        #pragma unroll
        for (int j = 0; j < 4; ++j)
            bf[j] = *reinterpret_cast<const short8*>(&Bs[(wn*64 + j*16 + l16)*32 + quad*8]);
        #pragma unroll
        for (int i = 0; i < 4; ++i)
            #pragma unroll
            for (int j = 0; j < 4; ++j)
                acc[i][j] = __builtin_amdgcn_mfma_f32_16x16x32_bf16(af[i], bf[j], acc[i][j], 0, 0, 0);
    }
    #pragma unroll
    for (int j = 0; j < 4; ++j) {
        const int gcol = nbase + wn*64 + j*16 + l16;
        const float bj = biasRow ? 0.0f : bias[gcol];
        #pragma unroll
        for (int i = 0; i < 4; ++i)
            #pragma unroll
            for (int r = 0; r < 4; ++r) {
                const int grow = rbase + wm*64 + i*16 + quad*4 + r;
                const float v = acc[i][j][r] + (biasRow ? bias[grow] : bj);
                outH[(size_t)grow*N + gcol] = __float2bfloat16(v);
            }
    }
}

// ---------------- fused wo-projection(+bias+resid) -> LDS -> xg2 f/b GEMMs ----------------
// Block = 64 rows; grid 512. Phase 1: x2(64x256) = Oh(64x512)@woT^T + bo + y1h.
// x2 kept ONLY in LDS (pad-264: 132 dwords = 4 mod 32 -> 2-way reads). Phase 2:
// xg2{f,b}(64x768) = x2 @ g2T^T, 6 col-tiles of 128, K=256.
// Epilogue scales x-gates by GS_ZR / GS_N for the exp2-domain GRU.
__global__ __launch_bounds__(256) void k_wo_xg2(const bf16* __restrict__ Oh,
        const bf16* __restrict__ woT, const float* __restrict__ bo,
        const bf16* __restrict__ y1h,
        const bf16* __restrict__ g2fT, const bf16* __restrict__ g2bT,
        const float* __restrict__ g2f_b, const float* __restrict__ g2b_b,
        bf16* __restrict__ xg2f, bf16* __restrict__ xg2b)
{
    __shared__ short x2_s[64*264];   // 33792 B
    __shared__ short As[64*32];      //  4096 B
    __shared__ short Bs[256*32];     // 16384 B (phase1 full; phase2 uses first 8 KB)
    const int rbase = blockIdx.x * 64;
    const int tid  = threadIdx.x;
    const int lane = tid & 63;
    const int wv   = tid >> 6;
    const int l16  = lane & 15;
    const int quad = lane >> 4;

    // phase 1: M=64 (wave: 32 rows), N=256 (wave: 128 cols), K=512 (16 kt)
    {
        const int wm = wv & 1, wn = wv >> 1;
        floatx4 acc[2][8];
        #pragma unroll
        for (int i = 0; i < 2; ++i)
            #pragma unroll
            for (int j = 0; j < 8; ++j) acc[i][j] = (floatx4)0.0f;
        for (int kt = 0; kt < 16; ++kt) {
            if (kt) __syncthreads();
            {   // A: 64 rows, 4 thr/row, 8 shorts each
                const int row = tid >> 2, koff = (tid & 3)*8;
                *reinterpret_cast<float4*>(&As[row*32 + koff]) =
                    *reinterpret_cast<const float4*>(&Oh[(size_t)(rbase + row)*HD + kt*32 + koff]);
                // B: woT 256 rows, 1 thr/row, 32 shorts each (4 x float4)
                const float4* g = reinterpret_cast<const float4*>(&woT[(size_t)tid*HD + kt*32]);
                float4* l = reinterpret_cast<float4*>(&Bs[tid*32]);
                l[0] = g[0]; l[1] = g[1]; l[2] = g[2]; l[3] = g[3];
            }
            __syncthreads();
            short8 af[2], bf[8];
            #pragma unroll
            for (int i = 0; i < 2; ++i)
                af[i] = *reinterpret_cast<const short8*>(&As[(wm*32 + i*16 + l16)*32 + quad*8]);
            #pragma unroll
            for (int j = 0; j < 8; ++j)
                bf[j] = *reinterpret_cast<const short8*>(&Bs[(wn*128 + j*16 + l16)*32 + quad*8]);
            #pragma unroll
            for (int i = 0; i < 2; ++i)
                #pragma unroll
                for (int j = 0; j < 8; ++j)
                    acc[i][j] = __builtin_amdgcn_mfma_f32_16x16x32_bf16(af[i], bf[j], acc[i][j], 0, 0, 0);
        }
        // epilogue: + bo + resid(y1h) -> x2_s
        #pragma unroll
        for (int j = 0; j < 8; ++j) {
            const int col = wn*128 + j*16 + l16;
            const float bj = bo[col];
            #pragma unroll
            for (int i = 0; i < 2; ++i)
                #pragma unroll
                for (int r = 0; r < 4; ++r) {
                    const int m = wm*32 + i*16 + quad*4 + r;
                    float v = acc[i][j][r] + bj +
                        __bfloat162float(y1h[(size_t)(rbase + m)*M2 + col]);
                    bf16 h = __float2bfloat16(v);
                    x2_s[m*264 + col] = *reinterpret_cast<short*>(&h);
                }
        }
    }
    __syncthreads();

    // phase 2: 6 col-tiles, M=64 (wave: 32 rows), N=128 (wave: 64 cols), K=256 (8 kt)
    const int wm = wv & 1, wn = wv >> 1;
    for (int ct = 0; ct < 6; ++ct) {
        const bf16* Bt = (ct < 3 ? g2fT : g2bT) + (size_t)(ct % 3)*128*M2;
        const float* bias = (ct < 3 ? g2f_b : g2b_b);
        bf16* outp = (ct < 3 ? xg2f : xg2b);
        const int cbase = (ct % 3)*128;
        const float gs = ((ct % 3) == 2) ? GS_N : GS_ZR;   // exp2-domain gate scale
        floatx4 acc[2][4];
        #pragma unroll
        for (int i = 0; i < 2; ++i)
            #pragma unroll
            for (int j = 0; j < 4; ++j) acc[i][j] = (floatx4)0.0f;
        for (int kt = 0; kt < 8; ++kt) {
            __syncthreads();
            {   // stage weight tile [128 rows][32 k]: 2 thr/row
                const int row = tid >> 1, koff = (tid & 1)*16;
                const float4* g = reinterpret_cast<const float4*>(&Bt[(size_t)row*M2 + kt*32 + koff]);
                float4* l = reinterpret_cast<float4*>(&Bs[row*32 + koff]);
                l[0] = g[0]; l[1] = g[1];
            }
            __syncthreads();
            short8 af[2], bf[4];
            #pragma unroll
            for (int i = 0; i < 2; ++i)
                af[i] = *reinterpret_cast<const short8*>(
                    &x2_s[(wm*32 + i*16 + l16)*264 + kt*32 + quad*8]);
            #pragma unroll
            for (int j = 0; j < 4; ++j)
                bf[j] = *reinterpret_cast<const short8*>(&Bs[(wn*64 + j*16 + l16)*32 + quad*8]);
            #pragma unroll
            for (int i = 0; i < 2; ++i)
                #pragma unroll
                for (int j = 0; j < 4; ++j)
                    acc[i][j] = __builtin_amdgcn_mfma_f32_16x16x32_bf16(af[i], bf[j], acc[i][j], 0, 0, 0);
        }
        #pragma unroll
        for (int j = 0; j < 4; ++j) {
            const int colg = cbase + wn*64 + j*16 + l16;
            const float bj = bias[colg];
            #pragma unroll
            for (int i = 0; i < 2; ++i)
                #pragma unroll
                for (int r = 0; r < 4; ++r) {
                    const int grow = rbase + wm*32 + i*16 + quad*4 + r;
                    outp[(size_t)grow*G3 + colg] = __float2bfloat16((acc[i][j][r] + bj) * gs);
                }
        }
    }
}

// ---------------- MFMA-batched GRU scan (exp2-domain gates; dense head fused) ----------------
// Gate math is in exp2 domain: the x-gates arrive pre-scaled (GS_ZR for z,r; GS_N for n),
// the recurrent weights/biases are scaled the same way in wfrag/bz4/br4/bn4 below. This
// replaces the old sigmoid/tanh (each a full IEEE divide + exp = ~12 VALU ops) with
// v_exp_f32 + v_rcp_f32 (2 trans ops) per gate -- the scan's critical path is VALU-issue
// bound (per-active-CU VALUBusy ~82% at r0), so this is the direct lever.
__device__ __forceinline__ float bfbits2f(unsigned short u){
    return __uint_as_float(((unsigned)u) << 16);
}

__global__ __launch_bounds__(512, 1) void k_gru(const bf16* __restrict__ xg_f,
        const bf16* __restrict__ xg_b, const float* __restrict__ wh_f,
        const float* __restrict__ wh_b, const float* __restrict__ b_f,
        const float* __restrict__ b_b, bf16* __restrict__ yseq,
        const float* __restrict__ dw, float* __restrict__ outp)
{
    const int dir   = blockIdx.y;
    const int bbase = blockIdx.x * 16;
    const bf16* xg  = dir ? xg_b : xg_f;            // [B*T, 3U] (pre-scaled)
    const float* wh = dir ? wh_b : wh_f;            // [U, 3U]
    const float* bh = (dir ? b_b : b_f) + G3;       // b[1]
    const int tid  = threadIdx.x;
    const int lane = tid & 63;
    const int wv   = tid >> 6;       // 0..7
    const int l16  = lane & 15;
    const int quad = lane >> 4;
    const int cb   = wv*16 + quad*4; // this lane's 4 gate cols
    const int brow = bbase + l16;    // this lane's batch

    short8 wfrag[3][4];
    #pragma unroll
    for (int g = 0; g < 3; ++g) {
        const float gsc = (g == 2) ? GS_N : GS_ZR;
        #pragma unroll
        for (int kt = 0; kt < 4; ++kt)
            #pragma unroll
            for (int j = 0; j < 8; ++j)
                reinterpret_cast<bf16*>(&wfrag[g][kt])[j] = __float2bfloat16(gsc *
                    wh[(size_t)(kt*32 + quad*8 + j)*G3 + g*U + wv*16 + l16]);
    }

    floatx4 bz4, br4, bn4;
    #pragma unroll
    for (int r = 0; r < 4; ++r) {
        bz4[r] = GS_ZR * bh[      cb + r];
        br4[r] = GS_ZR * bh[U   + cb + r];
        bn4[r] = GS_N  * bh[2*U + cb + r];
    }

    const int wr_idx = ((wv>>1)*64 + ((wv&1)*2 + (quad>>1))*16 + l16)*8 + (quad&1)*4;

    __shared__ __align__(16) short hbuf[2][2048];
    for (int i = tid; i < 2*2048; i += 512) (&hbuf[0][0])[i] = 0;
    __syncthreads();

    float hprev[4] = {0.f, 0.f, 0.f, 0.f};

    const int t0 = dir ? T-1 : 0;
    const ptrdiff_t xstr = dir ? -(ptrdiff_t)G3 : (ptrdiff_t)G3;
    const ptrdiff_t ystr = dir ? -(ptrdiff_t)M2 : (ptrdiff_t)M2;
    const bf16* xp = xg + ((size_t)brow*T + t0)*G3 + cb;
    bf16* yp = yseq ? (yseq + ((size_t)brow*T + t0)*M2 + dir*U + cb) : nullptr;

    ushort4_t xs[2][3];
    #pragma unroll
    for (int s = 0; s < 2; ++s) {
        xs[s][0] = *reinterpret_cast<const ushort4_t*>(xp);
        xs[s][1] = *reinterpret_cast<const ushort4_t*>(xp + U);
        xs[s][2] = *reinterpret_cast<const ushort4_t*>(xp + 2*U);
        xp += xstr;
    }

    for (int step2 = 0; step2 < T; step2 += 2) {
        #pragma unroll
        for (int u = 0; u < 2; ++u) {
            short8 hfrag[4];
            #pragma unroll
            for (int kt = 0; kt < 4; ++kt)
                hfrag[kt] = *reinterpret_cast<const short8*>(
                    &hbuf[u][(kt*64 + lane)*8]);
            // fold x-gate into MFMA C-in for z,r (executes under ds_read latency);
            // xn cannot fold (only the recurrent part is multiplied by r)
            floatx4 cz, cr;
            float xnv[4];
            #pragma unroll
            for (int r = 0; r < 4; ++r) {
                cz[r]  = bz4[r] + bfbits2f(xs[u][0][r]);
                cr[r]  = br4[r] + bfbits2f(xs[u][1][r]);
                xnv[r] = bfbits2f(xs[u][2][r]);
            }
            // refill xs[u] for step t+2 (latency hidden by ~1 substep)
            xs[u][0] = *reinterpret_cast<const ushort4_t*>(xp);
            xs[u][1] = *reinterpret_cast<const ushort4_t*>(xp + U);
            xs[u][2] = *reinterpret_cast<const ushort4_t*>(xp + 2*U);
            xp += xstr;
            floatx4 az = __builtin_amdgcn_mfma_f32_16x16x32_bf16(wfrag[0][0], hfrag[0], cz, 0, 0, 0);
            floatx4 ar = __builtin_amdgcn_mfma_f32_16x16x32_bf16(wfrag[1][0], hfrag[0], cr, 0, 0, 0);
            floatx4 an = __builtin_amdgcn_mfma_f32_16x16x32_bf16(wfrag[2][0], hfrag[0], bn4, 0, 0, 0);
            #pragma unroll
            for (int kt = 1; kt < 4; ++kt) {
                az = __builtin_amdgcn_mfma_f32_16x16x32_bf16(wfrag[0][kt], hfrag[kt], az, 0, 0, 0);
                ar = __builtin_amdgcn_mfma_f32_16x16x32_bf16(wfrag[1][kt], hfrag[kt], ar, 0, 0, 0);
                an = __builtin_amdgcn_mfma_f32_16x16x32_bf16(wfrag[2][kt], hfrag[kt], an, 0, 0, 0);
            }
            ushort4_t hpk;
            #pragma unroll
            for (int r = 0; r < 4; ++r) {
                // z = sigmoid(a): az = -log2e*a  ->  z = rcp(1 + 2^az)
                const float z  = __builtin_amdgcn_rcpf(1.0f + __builtin_amdgcn_exp2f(az[r]));
                const float rr = __builtin_amdgcn_rcpf(1.0f + __builtin_amdgcn_exp2f(ar[r]));
                // n = tanh(a): arg = 2log2e*a  ->  n = 1 - 2*rcp(1 + 2^arg)
                const float en = __builtin_amdgcn_exp2f(fmaf(rr, an[r], xnv[r]));
                const float n  = fmaf(-2.0f, __builtin_amdgcn_rcpf(1.0f + en), 1.0f);
                const float hnew = fmaf(z, hprev[r] - n, n);
                hprev[r] = hnew;
                bf16 hb = __float2bfloat16(hnew);
                hpk[r] = *reinterpret_cast<unsigned short*>(&hb);
            }
            *reinterpret_cast<ushort4_t*>(&hbuf[u^1][wr_idx]) = hpk;
            if (yp) {
                *reinterpret_cast<ushort4_t*>(yp) = hpk;
                yp += ystr;
            }
            asm volatile("" ::: "memory");
            __builtin_amdgcn_s_waitcnt(0xC07F);
            __builtin_amdgcn_s_barrier();
            asm volatile("" ::: "memory");
        }
    }
    if (dw) {   // fused dense head: partial dot + device atomicAdd (out pre-inited with db)
        float partial = 0.0f;
        #pragma unroll
        for (int r = 0; r < 4; ++r) partial += hprev[r] * dw[dir*U + cb + r];
        atomicAdd(&outp[brow], partial);
    }
}

// ---------------- MFMA flash attention (unchanged) ----------------
__global__ __launch_bounds__(256) void k_attn(const bf16* __restrict__ Q,
        const bf16* __restrict__ Kp, const bf16* __restrict__ VT,
        bf16* __restrict__ O)
{
    __shared__ short k_s[64*136];
    __shared__ short vt_s[128*72];
    __shared__ short p_s[64*72];
    const int qt = blockIdx.x;
    const int b  = blockIdx.y;
    const int h  = blockIdx.z;
    const int tid  = threadIdx.x;
    const int lane = tid & 63;
    const int wv   = tid >> 6;
    const int l16  = lane & 15;
    const int quad = lane >> 4;

    short8 qfrag[4];
    {
        const size_t qoff = (size_t)(b*T + qt*64 + wv*16 + l16)*HD + h*KD + quad*8;
        #pragma unroll
        for (int kt = 0; kt < 4; ++kt)
            qfrag[kt] = *reinterpret_cast<const short8*>(&Q[qoff + kt*32]);
    }

    floatx4 Oa[8];
    #pragma unroll
    for (int nf = 0; nf < 8; ++nf) Oa[nf] = (floatx4)0.0f;
    float mrun = -1e30f, lrun = 0.0f;

    for (int kg = 0; kg < 8; ++kg) {
        __syncthreads();
        #pragma unroll
        for (int it = 0; it < 4; ++it) {
            const int linear = it*256 + tid;
            const int key = linear >> 4;
            const int dc  = linear & 15;
            const float4 v = *reinterpret_cast<const float4*>(
                &Kp[(size_t)(b*T + kg*64 + key)*HD + h*KD + dc*8]);
            *reinterpret_cast<float4*>(&k_s[key*136 + dc*8]) = v;
        }
        #pragma unroll
        for (int it = 0; it < 4; ++it) {
            const int linear = it*256 + tid;
            const int d  = linear >> 3;
            const int kc = linear & 7;
            const float4 v = *reinterpret_cast<const float4*>(
                &VT[(size_t)(h*KD + d)*BT + b*T + kg*64 + kc*8]);
            *reinterpret_cast<float4*>(&vt_s[d*72 + kc*8]) = v;
        }
        __syncthreads();
        floatx4 s[4];
        #pragma unroll
        for (int kb = 0; kb < 4; ++kb) s[kb] = (floatx4)0.0f;
        #pragma unroll
        for (int kt = 0; kt < 4; ++kt) {
            #pragma unroll
            for (int kb = 0; kb < 4; ++kb) {
                const short8 af = *reinterpret_cast<const short8*>(
                    &k_s[(kb*16 + l16)*136 + kt*32 + quad*8]);
                s[kb] = __builtin_amdgcn_mfma_f32_16x16x32_bf16(af, qfrag[kt], s[kb], 0, 0, 0);
            }
        }
        float kmax = -1e30f;
        #pragma unroll
        for (int kb = 0; kb < 4; ++kb)
            #pragma unroll
            for (int r = 0; r < 4; ++r) {
                s[kb][r] *= 0.08838834764831845f;
                kmax = fmaxf(kmax, s[kb][r]);
            }
        kmax = fmaxf(kmax, __shfl_xor(kmax, 16));
        kmax = fmaxf(kmax, __shfl_xor(kmax, 32));
        const float mnew  = fmaxf(mrun, kmax);
        const float alpha = __expf(mrun - mnew);
        float psum = 0.0f;
        #pragma unroll
        for (int kb = 0; kb < 4; ++kb)
            #pragma unroll
            for (int r = 0; r < 4; ++r) {
                const float p = __expf(s[kb][r] - mnew);
                s[kb][r] = p;
                psum += p;
            }
        psum += __shfl_xor(psum, 16);
        psum += __shfl_xor(psum, 32);
        lrun = lrun*alpha + psum;
        mrun = mnew;
        #pragma unroll
        for (int r = 0; r < 4; ++r) {
            const float ar = __shfl(alpha, quad*4 + r);
            #pragma unroll
            for (int nf = 0; nf < 8; ++nf) Oa[nf][r] *= ar;
        }
        bf16* pb = reinterpret_cast<bf16*>(p_s);
        #pragma unroll
        for (int kb = 0; kb < 4; ++kb)
            #pragma unroll
            for (int r = 0; r < 4; ++r)
                pb[(wv*16 + l16)*72 + kb*16 + quad*4 + r] = __float2bfloat16(s[kb][r]);
        #pragma unroll
        for (int kt2 = 0; kt2 < 2; ++kt2) {
            const short8 pf = *reinterpret_cast<const short8*>(
                &p_s[(wv*16 + l16)*72 + kt2*32 + quad*8]);
            #pragma unroll
            for (int nf = 0; nf < 8; ++nf) {
                const short8 vf = *reinterpret_cast<const short8*>(
                    &vt_s[(nf*16 + l16)*72 + kt2*32 + quad*8]);
                Oa[nf] = __builtin_amdgcn_mfma_f32_16x16x32_bf16(pf, vf, Oa[nf], 0, 0, 0);
            }
        }
    }
    float linv[4];
    #pragma unroll
    for (int r = 0; r < 4; ++r) linv[r] = 1.0f / __shfl(lrun, quad*4 + r);
    #pragma unroll
    for (int nf = 0; nf < 8; ++nf)
        #pragma unroll
        for (int r = 0; r < 4; ++r) {
            const size_t row = (size_t)(b*T + qt*64 + wv*16 + quad*4 + r);
            O[row*HD + h*KD + nf*16 + l16] = __float2bfloat16(Oa[nf][r] * linv[r]);
        }
}

extern "C" void kernel_launch(void* const* d_in, const int* in_sizes, int n_in,
                              void* d_out, int out_size, void* d_ws, size_t ws_size,
                              hipStream_t stream)
{
    const float* inputs  = (const float*)d_in[0];
    const float* conv_w  = (const float*)d_in[1];
    const float* conv_b  = (const float*)d_in[2];
    const float* bn_g    = (const float*)d_in[3];
    const float* bn_b    = (const float*)d_in[4];
    const float* bn_m    = (const float*)d_in[5];
    const float* bn_v    = (const float*)d_in[6];
    const float* g1f_wx  = (const float*)d_in[7];
    const float* g1f_wh  = (const float*)d_in[8];
    const float* g1f_b   = (const float*)d_in[9];
    const float* g1b_wx  = (const float*)d_in[10];
    const float* g1b_wh  = (const float*)d_in[11];
    const float* g1b_b   = (const float*)d_in[12];
    const float* wq      = (const float*)d_in[13];
    const float* bq      = (const float*)d_in[14];
    const float* wk      = (const float*)d_in[15];
    const float* bk      = (const float*)d_in[16];
    const float* wv_     = (const float*)d_in[17];
    const float* bv      = (const float*)d_in[18];
    const float* wo      = (const float*)d_in[19];
    const float* bo      = (const float*)d_in[20];
    const float* g2f_wx  = (const float*)d_in[21];
    const float* g2f_wh  = (const float*)d_in[22];
    const float* g2f_b   = (const float*)d_in[23];
    const float* g2b_wx  = (const float*)d_in[24];
    const float* g2b_wh  = (const float*)d_in[25];
    const float* g2b_b   = (const float*)d_in[26];
    const float* dense_w = (const float*)d_in[27];
    const float* dense_b = (const float*)d_in[28];
    float* out = (float*)d_out;
    (void)in_sizes; (void)n_in; (void)out_size; (void)ws_size;

    // ---- workspace (float-slot offsets into 128 MiB = 33,554,432 fslots) ----
    float* ws = (float*)d_ws;
    bf16* wb = (bf16*)ws;
    bf16* g1fT = wb;            // [384,64]
    bf16* g1bT = wb + 24576;
    bf16* wqT  = wb + 49152;    // [512,256]
    bf16* wkT  = wb + 180224;
    bf16* wvT  = wb + 311296;   // [512,256] -> GEMM-A for V^T
    bf16* woT  = wb + 442368;   // [256,512]
    bf16* g2fT = wb + 573440;   // [384,256]
    bf16* g2bT = wb + 671744;
    bf16* cwT  = wb + 770048;   // [64,192]  ends 782336 < 786432

    bf16*  xg1f = (bf16*)(ws + 1441792);    // [B*T,384] bf16
    bf16*  xg1b = (bf16*)(ws + 7733248);    // [B*T,384] bf16 (ends 14024704)
    bf16*  y1h  = (bf16*)(ws + 26607616);   // [B*T,256]
    bf16*  qh   = (bf16*)(ws + 393216);     // [B*T,512]
    bf16*  kh   = (bf16*)(ws + 8781824);    // [B*T,512]  dead after attn
    bf16*  vtg  = (bf16*)(ws + 17170432);   // [512,B*T]  dead after attn
    bf16*  Oh   = qh;                       // attention output in-place (live in wo_xg2)
    bf16*  xg2f = (bf16*)(ws + 8781824);    // over dead kh  (Oh/y1h NOT aliased)
    bf16*  xg2b = (bf16*)(ws + 17170432);   // over dead vtg

    // 0. fused weight casts + out init (one launch)
    k_wcast_all<<<dim3(512, 9), 256, 0, stream>>>(g1f_wx, g1b_wx, wq, wk, wv_,
                                                  wo, g2f_wx, g2b_wx, conv_w,
                                                  dense_b, out, wb);
    // 1. conv+BN+ReLU (MFMA im2col) + xg1 f/b, fused
    k_conv_xg<<<dim3(4, B), 256, 0, stream>>>(inputs, cwT, conv_b,
                                              bn_g, bn_b, bn_m, bn_v,
                                              g1fT, g1bT, g1f_b, g1b_b, xg1f, xg1b);
    // 2. GRU1 scan -> y1h
    k_gru<<<dim3(4, 2), 512, 0, stream>>>(xg1f, xg1b, g1f_wh, g1b_wh,
                                          g1f_b, g1b_b, y1h, nullptr, nullptr);
    // 3. Q, K, V^T in one launch
    k_gemm3<<<dim3(4, 256, 3), 256, 0, stream>>>(y1h, wqT, wkT, wvT,
                                                 bq, bk, bv, qh, kh, vtg);
    // 4. MFMA flash attention, O in-place over Q
    k_attn<<<dim3(T/64, B, NH), 256, 0, stream>>>(qh, kh, vtg, Oh);
    // 5. wo-projection + bias + resid -> (LDS) -> xg2 f/b, fused
    k_wo_xg2<<<dim3(BT/64), 256, 0, stream>>>(Oh, woT, bo, y1h,
                                              g2fT, g2bT, g2f_b, g2b_b, xg2f, xg2b);
    // 6. GRU2 scan, dense head fused (atomicAdd onto pre-inited out)
    k_gru<<<dim3(4, 2), 512, 0, stream>>>(xg2f, xg2b, g2f_wh, g2b_wh,
                                          g2f_b, g2b_b, nullptr, dense_w, out);
}